// Round 2
// baseline (2565.698 us; speedup 1.0000x reference)
//
#include <hip/hip_runtime.h>
#include <hip/hip_bf16.h>

// Problem constants
#define Bb 256
#define Ss 64
#define Nn_ 17
#define CIN 3
#define HID 64
#define HEADS 2
#define CCH 128        // HEADS*HID
#define Gg 16384       // B*S
#define Ee 81          // 64 edges + 17 self loops
#define LSTM_IN 2176   // 17*128
#define OUT_ 128
#define G4 512         // 4*OUT
#define NCLS 10
#define Tt 64

// ---------------- setup: build src/dst + dst-CSR (edge structure shared by all graphs)
__global__ void k_setup(const int* __restrict__ edge_index, int* __restrict__ csr) {
    // layout: src[81] | dst[81] | off[18] | eid[81]
    if (threadIdx.x == 0 && blockIdx.x == 0) {
        int* src = csr;
        int* dst = csr + Ee;
        int* off = csr + 2 * Ee;
        int* eid = csr + 2 * Ee + Nn_ + 1;
        for (int e = 0; e < 64; e++) { src[e] = edge_index[e]; dst[e] = edge_index[64 + e]; }
        for (int n = 0; n < Nn_; n++) { src[64 + n] = n; dst[64 + n] = n; }
        int cnt[Nn_];
        for (int n = 0; n < Nn_; n++) cnt[n] = 0;
        for (int e = 0; e < Ee; e++) cnt[dst[e]]++;
        off[0] = 0;
        for (int n = 0; n < Nn_; n++) off[n + 1] = off[n] + cnt[n];
        int pos[Nn_];
        for (int n = 0; n < Nn_; n++) pos[n] = off[n];
        for (int e = 0; e < Ee; e++) eid[pos[dst[e]]++] = e;
    }
}

// ---------------- out-of-place tiled GEMM, C[M,128] = A[M,K] * B[K,128] (used for layer 0, K=3)
#define BM 64
#define BN 64
#define BK 16
__global__ __launch_bounds__(256) void k_gemm_nn(const float* __restrict__ A,
                                                 const float* __restrict__ Bm,
                                                 float* __restrict__ Cm,
                                                 int M, int Nc, int K) {
    __shared__ float As[BK][BM];
    __shared__ float Bs[BK][BN];
    const int bm = blockIdx.x * BM, bn = blockIdx.y * BN;
    const int t = threadIdx.x;
    const int tx = t % 16, ty = t / 16;
    float acc[4][4] = {};
    for (int k0 = 0; k0 < K; k0 += BK) {
#pragma unroll
        for (int i = 0; i < 4; i++) {
            int e = t * 4 + i;
            int m = e / BK, k = e % BK;
            int gk = k0 + k;
            As[k][m] = (gk < K) ? A[(long)(bm + m) * K + gk] : 0.f;
        }
#pragma unroll
        for (int i = 0; i < 4; i++) {
            int e = t * 4 + i;
            int k = e / BN, n = e % BN;
            int gk = k0 + k;
            Bs[k][n] = (gk < K) ? Bm[(long)gk * Nc + bn + n] : 0.f;
        }
        __syncthreads();
#pragma unroll
        for (int kk = 0; kk < BK; kk++) {
            float a[4], b[4];
#pragma unroll
            for (int i = 0; i < 4; i++) a[i] = As[kk][ty * 4 + i];
#pragma unroll
            for (int j = 0; j < 4; j++) b[j] = Bs[kk][tx * 4 + j];
#pragma unroll
            for (int i = 0; i < 4; i++)
#pragma unroll
                for (int j = 0; j < 4; j++) acc[i][j] += a[i] * b[j];
        }
        __syncthreads();
    }
#pragma unroll
    for (int i = 0; i < 4; i++)
#pragma unroll
        for (int j = 0; j < 4; j++)
            Cm[(long)(bm + ty * 4 + i) * Nc + bn + tx * 4 + j] = acc[i][j];
}

// ---------------- IN-PLACE GEMM: HB[M,128] = HB[M,128] @ W[128,128]
// Safe in-place: each block covers the FULL output width for rows [bm,bm+64),
// so it reads only rows it itself writes, and all global reads (K-loop)
// complete before any C write (accumulators in registers). Blocks are
// row-disjoint -> no cross-block hazard regardless of dispatch order.
__global__ __launch_bounds__(256) void k_gemm128_ip(float* __restrict__ HB,
                                                    const float* __restrict__ W) {
    __shared__ float As[16][64];
    __shared__ float Bs[16][128];
    const long bm = (long)blockIdx.x * 64;
    const int t = threadIdx.x;
    const int tx = t % 32, ty = t / 32;  // cols tx*4.., rows ty*8..
    float acc[8][4] = {};
    const float* A = HB + bm * CCH;
    for (int k0 = 0; k0 < CCH; k0 += 16) {
#pragma unroll
        for (int i = 0; i < 4; i++) {
            int e = t * 4 + i;            // 1024 = 16*64
            int m = e >> 4, k = e & 15;
            As[k][m] = A[m * CCH + k0 + k];
        }
#pragma unroll
        for (int i = 0; i < 8; i++) {
            int e = t * 8 + i;            // 2048 = 16*128
            int k = e >> 7, n = e & 127;
            Bs[k][n] = W[(k0 + k) * CCH + n];
        }
        __syncthreads();
#pragma unroll
        for (int kk = 0; kk < 16; kk++) {
            float a[8], b[4];
#pragma unroll
            for (int i = 0; i < 8; i++) a[i] = As[kk][ty * 8 + i];
#pragma unroll
            for (int j = 0; j < 4; j++) b[j] = Bs[kk][tx * 4 + j];
#pragma unroll
            for (int i = 0; i < 8; i++)
#pragma unroll
                for (int j = 0; j < 4; j++) acc[i][j] += a[i] * b[j];
        }
        __syncthreads();
    }
    float* C = HB + bm * CCH;
#pragma unroll
    for (int i = 0; i < 8; i++)
#pragma unroll
        for (int j = 0; j < 4; j++)
            C[(ty * 8 + i) * CCH + tx * 4 + j] = acc[i][j];
}

// ---------------- tiled GEMM, C[M,N] = A[M,K] * B[N,K]^T + b1[N] + b2[N]
__global__ __launch_bounds__(256) void k_gemm_nt(const float* __restrict__ A,
                                                 const float* __restrict__ Bm,
                                                 float* __restrict__ Cm,
                                                 const float* __restrict__ b1,
                                                 const float* __restrict__ b2,
                                                 int M, int Nc, int K) {
    __shared__ float As[BK][BM];
    __shared__ float Bs[BK][BN];
    const int bm = blockIdx.x * BM, bn = blockIdx.y * BN;
    const int t = threadIdx.x;
    const int tx = t % 16, ty = t / 16;
    float acc[4][4] = {};
    for (int k0 = 0; k0 < K; k0 += BK) {
#pragma unroll
        for (int i = 0; i < 4; i++) {
            int e = t * 4 + i;
            int m = e / BK, k = e % BK;
            int gk = k0 + k;
            As[k][m] = (gk < K) ? A[(long)(bm + m) * K + gk] : 0.f;
        }
#pragma unroll
        for (int i = 0; i < 4; i++) {
            int e = t * 4 + i;
            int n = e / BK, k = e % BK;
            int gk = k0 + k;
            Bs[k][n] = (gk < K) ? Bm[(long)(bn + n) * K + gk] : 0.f;
        }
        __syncthreads();
#pragma unroll
        for (int kk = 0; kk < BK; kk++) {
            float a[4], b[4];
#pragma unroll
            for (int i = 0; i < 4; i++) a[i] = As[kk][ty * 4 + i];
#pragma unroll
            for (int j = 0; j < 4; j++) b[j] = Bs[kk][tx * 4 + j];
#pragma unroll
            for (int i = 0; i < 4; i++)
#pragma unroll
                for (int j = 0; j < 4; j++) acc[i][j] += a[i] * b[j];
        }
        __syncthreads();
    }
#pragma unroll
    for (int i = 0; i < 4; i++)
#pragma unroll
        for (int j = 0; j < 4; j++) {
            int gn = bn + tx * 4 + j;
            Cm[(long)(bm + ty * 4 + i) * Nc + gn] = acc[i][j] + b1[gn] + b2[gn];
        }
}

// ---------------- per-graph GAT attention + aggregation (in-place on h)
__global__ __launch_bounds__(256) void k_gat_attn(float* __restrict__ h,
                                                  const float* __restrict__ a_src,
                                                  const float* __restrict__ a_dst,
                                                  const float* __restrict__ bias,
                                                  const int* __restrict__ csr,
                                                  int relu_flag) {
    const int* srcA = csr;
    const int* dstA = csr + Ee;
    const int* off  = csr + 2 * Ee;
    const int* eid  = csr + 2 * Ee + Nn_ + 1;
    const int g = blockIdx.x, t = threadIdx.x;
    __shared__ float hs[Nn_ * CCH];
    __shared__ float as_[Nn_ * 2], ad_[Nn_ * 2];
    __shared__ float ev[Ee * 2];
    __shared__ float mden[Nn_ * 2 * 2];
    float* hg = h + (long)g * Nn_ * CCH;
    for (int i = t; i < Nn_ * CCH; i += 256) hs[i] = hg[i];
    __syncthreads();
    if (t < Nn_ * 2) {
        int n = t / 2, hh = t % 2;
        float s1 = 0.f, s2 = 0.f;
        for (int d = 0; d < HID; d++) {
            float hv = hs[n * CCH + hh * HID + d];
            s1 += hv * a_src[hh * HID + d];
            s2 += hv * a_dst[hh * HID + d];
        }
        as_[t] = s1;
        ad_[t] = s2;
    }
    __syncthreads();
    if (t < Ee * 2) {
        int e = t / 2, hh = t % 2;
        float x = as_[srcA[e] * 2 + hh] + ad_[dstA[e] * 2 + hh];
        ev[t] = (x > 0.f) ? x : 0.2f * x;
    }
    __syncthreads();
    if (t < Nn_ * 2) {
        int n = t / 2, hh = t % 2;
        float m = -1e30f;
        for (int p = off[n]; p < off[n + 1]; p++) m = fmaxf(m, ev[eid[p] * 2 + hh]);
        float den = 0.f;
        for (int p = off[n]; p < off[n + 1]; p++) den += expf(ev[eid[p] * 2 + hh] - m);
        mden[t] = m;
        mden[Nn_ * 2 + t] = den;
    }
    __syncthreads();
    if (t < Ee * 2) {
        int e = t / 2, hh = t % 2;
        int n = dstA[e];
        float m = mden[n * 2 + hh], den = mden[Nn_ * 2 + n * 2 + hh];
        ev[t] = expf(ev[t] - m) / (den + 1e-16f);
    }
    __syncthreads();
    for (int i = t; i < Nn_ * CCH; i += 256) {
        int n = i / CCH, c = i % CCH, hh = c >> 6;
        float acc = 0.f;
        for (int p = off[n]; p < off[n + 1]; p++) {
            int e = eid[p];
            acc += ev[e * 2 + hh] * hs[srcA[e] * CCH + c];
        }
        acc += bias[c];
        if (relu_flag) acc = fmaxf(acc, 0.f);
        hg[i] = acc;
    }
}

// ---------------- LSTM recurrence: one block per batch row, whh rows in registers
__global__ __launch_bounds__(512, 1) void k_lstm(const float* __restrict__ XW,
                                                 const float* __restrict__ whh,
                                                 float* __restrict__ hseq) {
    const int b = blockIdx.x, j = threadIdx.x;  // j in [0,512): gate column
    float4 w[32];
#pragma unroll
    for (int k = 0; k < 32; k++) w[k] = ((const float4*)(whh + (long)j * OUT_))[k];
    __shared__ __align__(16) float h_s[OUT_];
    __shared__ float c_s[OUT_];
    __shared__ float gate_s[G4];
    if (j < OUT_) { h_s[j] = 0.f; c_s[j] = 0.f; }
    __syncthreads();
    for (int t = 0; t < Tt; t++) {
        float acc = XW[((long)b * Tt + t) * G4 + j];
#pragma unroll
        for (int k = 0; k < 32; k++) {
            float4 hv = ((const float4*)h_s)[k];
            acc += w[k].x * hv.x + w[k].y * hv.y + w[k].z * hv.z + w[k].w * hv.w;
        }
        gate_s[j] = acc;
        __syncthreads();
        if (j < OUT_) {
            float gi = gate_s[j], gf = gate_s[OUT_ + j], gg = gate_s[2 * OUT_ + j], go = gate_s[3 * OUT_ + j];
            float si = 1.f / (1.f + expf(-gi));
            float sf = 1.f / (1.f + expf(-gf));
            float so = 1.f / (1.f + expf(-go));
            float c = sf * c_s[j] + si * tanhf(gg);
            float hh = so * tanhf(c);
            c_s[j] = c;
            h_s[j] = hh;
            hseq[((long)b * Tt + t) * OUT_ + j] = hh;
        }
        __syncthreads();
    }
}

// ---------------- attention pooling + FC: one wave per batch row
__global__ __launch_bounds__(64) void k_attn_fc(const float* __restrict__ h2,
                                                const float* __restrict__ attn_w,
                                                const float* __restrict__ attn_b,
                                                const float* __restrict__ fc_w,
                                                const float* __restrict__ fc_b,
                                                float* __restrict__ out) {
    const int b = blockIdx.x, t = threadIdx.x;  // 64 threads = 1 wave
    __shared__ float aw[Tt];
    __shared__ float ctx[OUT_];
    const float* hb = h2 + (long)b * Tt * OUT_;
    float acc = 0.f;
    for (int d = 0; d < OUT_; d++) acc += hb[t * OUT_ + d] * attn_w[d];
    float sc = tanhf(acc + attn_b[0]);
    float m = sc;
#pragma unroll
    for (int o = 32; o > 0; o >>= 1) m = fmaxf(m, __shfl_xor(m, o));
    float ex = expf(sc - m);
    float sum = ex;
#pragma unroll
    for (int o = 32; o > 0; o >>= 1) sum += __shfl_xor(sum, o);
    aw[t] = ex / sum;
    __syncthreads();
    for (int d = t; d < OUT_; d += 64) {
        float c = 0.f;
        for (int tt = 0; tt < Tt; tt++) c += aw[tt] * hb[tt * OUT_ + d];
        ctx[d] = c;
    }
    __syncthreads();
    if (t < NCLS) {
        float o = fc_b[t];
        for (int d = 0; d < OUT_; d++) o += ctx[d] * fc_w[t * OUT_ + d];
        out[b * NCLS + t] = o;
    }
}

extern "C" void kernel_launch(void* const* d_in, const int* in_sizes, int n_in,
                              void* d_out, int out_size, void* d_ws, size_t ws_size,
                              hipStream_t stream) {
    const float* x          = (const float*)d_in[0];
    const int*   edge_index = (const int*)d_in[1];
    const float* gw[4]  = {(const float*)d_in[2], (const float*)d_in[6], (const float*)d_in[10], (const float*)d_in[14]};
    const float* gas[4] = {(const float*)d_in[3], (const float*)d_in[7], (const float*)d_in[11], (const float*)d_in[15]};
    const float* gad[4] = {(const float*)d_in[4], (const float*)d_in[8], (const float*)d_in[12], (const float*)d_in[16]};
    const float* gb[4]  = {(const float*)d_in[5], (const float*)d_in[9], (const float*)d_in[13], (const float*)d_in[17]};
    const float* wih0 = (const float*)d_in[18];
    const float* whh0 = (const float*)d_in[19];
    const float* bih0 = (const float*)d_in[20];
    const float* bhh0 = (const float*)d_in[21];
    const float* wih1 = (const float*)d_in[22];
    const float* whh1 = (const float*)d_in[23];
    const float* bih1 = (const float*)d_in[24];
    const float* bhh1 = (const float*)d_in[25];
    const float* attn_w = (const float*)d_in[26];
    const float* attn_b = (const float*)d_in[27];
    const float* fc_w   = (const float*)d_in[28];
    const float* fc_b   = (const float*)d_in[29];
    float* out = (float*)d_out;
    float* ws  = (float*)d_ws;

    // Workspace layout (peak 176.2 MB):
    //   buf : [0, 35,651,584)             GAT hidden, 142.6 MB  (single buffer, in-place)
    //   XW0 : [35,651,584, 44,040,192)    33.5 MB
    //   csr : 261 ints after XW0
    // After buf is dead (post XW0 GEMM), alias into buf:
    //   h1s = buf[0, 2,097,152) ; XW1 = buf[2,097,152, 10,485,760) ; h2s = buf[10,485,760, 12,582,912)
    const long GAT_ELEMS = (long)Gg * Nn_ * CCH;  // 35,651,584 floats
    float* buf = ws;
    float* XW0 = ws + GAT_ELEMS;
    int*   csr = (int*)(ws + GAT_ELEMS + 8388608L);
    float* h1s = buf;
    float* XW1 = buf + 2097152L;
    float* h2s = buf + 10485760L;

    k_setup<<<1, 1, 0, stream>>>(edge_index, csr);

    const int Mg = Gg * Nn_;  // 278528

    // GAT layer 0: x [Mg,3] @ gw0 [3,128] -> buf ; attn in-place (relu)
    dim3 l0Grid(Mg / BM, CCH / BN);  // 4352 x 2
    k_gemm_nn<<<l0Grid, 256, 0, stream>>>(x, gw[0], buf, Mg, CCH, CIN);
    k_gat_attn<<<Gg, 256, 0, stream>>>(buf, gas[0], gad[0], gb[0], csr, 1);
    // layers 1..3: in-place GEMM + in-place attention
    k_gemm128_ip<<<Mg / 64, 256, 0, stream>>>(buf, gw[1]);
    k_gat_attn<<<Gg, 256, 0, stream>>>(buf, gas[1], gad[1], gb[1], csr, 0);
    k_gemm128_ip<<<Mg / 64, 256, 0, stream>>>(buf, gw[2]);
    k_gat_attn<<<Gg, 256, 0, stream>>>(buf, gas[2], gad[2], gb[2], csr, 1);
    k_gemm128_ip<<<Mg / 64, 256, 0, stream>>>(buf, gw[3]);
    k_gat_attn<<<Gg, 256, 0, stream>>>(buf, gas[3], gad[3], gb[3], csr, 0);

    // LSTM layer 0: hoisted input GEMM (buf == lstm_in [16384,2176]) + recurrence
    dim3 lstmGrid(Gg / BM, G4 / BN);  // 256 x 8
    k_gemm_nt<<<lstmGrid, 256, 0, stream>>>(buf, wih0, XW0, bih0, bhh0, Gg, G4, LSTM_IN);
    k_lstm<<<Bb, 512, 0, stream>>>(XW0, whh0, h1s);

    // LSTM layer 1
    k_gemm_nt<<<lstmGrid, 256, 0, stream>>>(h1s, wih1, XW1, bih1, bhh1, Gg, G4, OUT_);
    k_lstm<<<Bb, 512, 0, stream>>>(XW1, whh1, h2s);

    // attention pooling + FC
    k_attn_fc<<<Bb, 64, 0, stream>>>(h2s, attn_w, attn_b, fc_w, fc_b, out);
}

// Round 3
// 1059.893 us; speedup vs baseline: 2.4207x; 2.4207x over previous
//
#include <hip/hip_runtime.h>
#include <hip/hip_bf16.h>

// Problem constants
#define Bb 256
#define Nn_ 17
#define CIN 3
#define HID 64
#define CCH 128        // HEADS*HID
#define Gg 16384       // B*S
#define Ee 81          // 64 edges + 17 self loops
#define LSTM_IN 2176   // 17*128
#define OUT_ 128
#define G4 512         // 4*OUT
#define NCLS 10
#define Tt 64
#define Mg (Gg * Nn_)  // 278528

typedef unsigned short u16;
typedef unsigned int u32;
typedef __attribute__((ext_vector_type(8))) short bf16x8;   // 8 bf16 = 4 VGPRs (guide §3)
typedef __attribute__((ext_vector_type(4))) float f32x4;

__device__ __forceinline__ u16 f2bf(float f) {   // RNE fp32->bf16
    u32 u = __float_as_uint(f);
    u += 0x7fffu + ((u >> 16) & 1u);
    return (u16)(u >> 16);
}

__device__ __forceinline__ void async16(const void* g, void* l) {
    // direct global->LDS, 16B per lane; LDS dest = wave-uniform base + lane*16
    __builtin_amdgcn_global_load_lds((__attribute__((address_space(1))) u32*)g,
                                     (__attribute__((address_space(3))) u32*)l, 16, 0, 0);
}

// ---------------- setup: build src/dst + dst-CSR (edge structure shared by all graphs)
__global__ void k_setup(const int* __restrict__ edge_index, int* __restrict__ csr) {
    if (threadIdx.x == 0 && blockIdx.x == 0) {
        int* src = csr;
        int* dst = csr + Ee;
        int* off = csr + 2 * Ee;
        int* eid = csr + 2 * Ee + Nn_ + 1;
        for (int e = 0; e < 64; e++) { src[e] = edge_index[e]; dst[e] = edge_index[64 + e]; }
        for (int n = 0; n < Nn_; n++) { src[64 + n] = n; dst[64 + n] = n; }
        int cnt[Nn_];
        for (int n = 0; n < Nn_; n++) cnt[n] = 0;
        for (int e = 0; e < Ee; e++) cnt[dst[e]]++;
        off[0] = 0;
        for (int n = 0; n < Nn_; n++) off[n + 1] = off[n] + cnt[n];
        int pos[Nn_];
        for (int n = 0; n < Nn_; n++) pos[n] = off[n];
        for (int e = 0; e < Ee; e++) eid[pos[dst[e]]++] = e;
    }
}

// ---------------- weight conversion fp32 -> bf16 (straight)
__global__ void k_convert(const float* __restrict__ in, u16* __restrict__ out, long n) {
    long i = (long)blockIdx.x * 256 + threadIdx.x;
    if (i < n) out[i] = f2bf(in[i]);
}
// ---------------- 128x128 weight: [k][n] -> bf16 [n][k] (transpose for MFMA B-operand)
__global__ void k_convert_t128(const float* __restrict__ in, u16* __restrict__ out) {
    int i = blockIdx.x * 256 + threadIdx.x;  // over 16384
    int n = i >> 7, k = i & 127;
    out[i] = f2bf(in[k * 128 + n]);
}

// ---------------- GAT layer 0: h[Mg,128] = x[Mg,3] @ W[3,128]  (bf16 out)
__global__ __launch_bounds__(256) void k_l0(const float* __restrict__ x,
                                            const float* __restrict__ W,
                                            u16* __restrict__ h) {
    __shared__ float ws[3 * 128];
    const int t = threadIdx.x;
    for (int i = t; i < 384; i += 256) ws[i] = W[i];
    __syncthreads();
    const long row = (long)blockIdx.x * 16 + (t >> 4);
    const int c0 = (t & 15) * 8;
    const float x0 = x[row * 3 + 0], x1 = x[row * 3 + 1], x2 = x[row * 3 + 2];
    union { uint4 u; u16 s[8]; } o;
#pragma unroll
    for (int j = 0; j < 8; j++) {
        float v = x0 * ws[c0 + j] + x1 * ws[128 + c0 + j] + x2 * ws[256 + c0 + j];
        o.s[j] = f2bf(v);
    }
    *(uint4*)(h + row * 128 + c0) = o.u;
}

// ---------------- bf16 MFMA GEMM: C[M,ldc] = A[M,K]bf16 @ Bt[N,K]bf16^T
// 128x128 tile per block (4 waves, each 64x64 via 4x4 of 16x16x32 MFMA),
// BK=64, global_load_lds width 16, XOR chunk swizzle (2 lanes/bank-group = free).
// OUT_BF16=1: bf16 C (no bias) -- in-place safe (full-width N, row-disjoint blocks).
// OUT_BF16=0: fp32 C with +b1[n]+b2[n].
template <int OUT_BF16>
__global__ __launch_bounds__(256) void k_gemm_mfma(const u16* __restrict__ A,
                                                   const u16* __restrict__ Bt,
                                                   void* __restrict__ Cv,
                                                   const float* __restrict__ b1,
                                                   const float* __restrict__ b2,
                                                   int K, int ldc) {
    __shared__ u16 ldsA[128 * 64];
    __shared__ u16 ldsB[128 * 64];
    const int w = threadIdx.x >> 6;
    const int lane = threadIdx.x & 63;
    const long bm = (long)blockIdx.x * 128;
    const int bn = blockIdx.y * 128;
    const int wm = (w & 1) * 64, wn = (w >> 1) * 64;
    const int q = lane >> 4, col = lane & 15;

    f32x4 acc[4][4] = {};

    for (int k0 = 0; k0 < K; k0 += 64) {
#pragma unroll
        for (int i = 0; i < 4; i++) {
            const int slot = (w * 4 + i) * 64 + lane;       // 0..1023
            const int r = slot >> 3, cs = slot & 7;
            const int cg = cs ^ (r & 7);                    // swizzled global chunk
            async16(A + (bm + r) * (long)K + k0 + cg * 8, ldsA + (w * 4 + i) * 512);
            async16(Bt + (long)(bn + r) * K + k0 + cg * 8, ldsB + (w * 4 + i) * 512);
        }
        __syncthreads();   // drains vmcnt (global_load_lds) + orders LDS
#pragma unroll
        for (int kk = 0; kk < 2; kk++) {
            bf16x8 af[4], bfr[4];
#pragma unroll
            for (int mt = 0; mt < 4; mt++) {
                const int m = wm + mt * 16 + col;
                const int cs = (kk * 4 + q) ^ (m & 7);
                af[mt] = *(const bf16x8*)&ldsA[m * 64 + cs * 8];
            }
#pragma unroll
            for (int nt = 0; nt < 4; nt++) {
                const int n = wn + nt * 16 + col;
                const int cs = (kk * 4 + q) ^ (n & 7);
                bfr[nt] = *(const bf16x8*)&ldsB[n * 64 + cs * 8];
            }
#pragma unroll
            for (int mt = 0; mt < 4; mt++)
#pragma unroll
                for (int nt = 0; nt < 4; nt++)
                    acc[mt][nt] = __builtin_amdgcn_mfma_f32_16x16x32_bf16(af[mt], bfr[nt], acc[mt][nt], 0, 0, 0);
        }
        __syncthreads();
    }
    // epilogue: C/D layout col=lane&15, row=quad*4+reg (m89-verified)
#pragma unroll
    for (int mt = 0; mt < 4; mt++)
#pragma unroll
        for (int nt = 0; nt < 4; nt++) {
            const int cg = bn + wn + nt * 16 + col;
            float bb = 0.f;
            if (!OUT_BF16) bb = b1[cg] + b2[cg];
#pragma unroll
            for (int r = 0; r < 4; r++) {
                const long rg = bm + wm + mt * 16 + q * 4 + r;
                const float v = acc[mt][nt][r];
                if (OUT_BF16) ((u16*)Cv)[rg * ldc + cg] = f2bf(v);
                else          ((float*)Cv)[rg * ldc + cg] = v + bb;
            }
        }
}

// ---------------- per-graph GAT attention + aggregation (in-place on bf16 h)
__global__ __launch_bounds__(256) void k_gat_attn(u16* __restrict__ h,
                                                  const float* __restrict__ a_src,
                                                  const float* __restrict__ a_dst,
                                                  const float* __restrict__ bias,
                                                  const int* __restrict__ csr,
                                                  int relu_flag) {
    const int* srcA = csr;
    const int* dstA = csr + Ee;
    const int* off  = csr + 2 * Ee;
    const int* eid  = csr + 2 * Ee + Nn_ + 1;
    const int g = blockIdx.x, t = threadIdx.x;
    __shared__ float hs[Nn_ * CCH];
    __shared__ float as_[Nn_ * 2], ad_[Nn_ * 2];
    __shared__ float ev[Ee * 2];
    __shared__ float mden[Nn_ * 2 * 2];
    u32* hg = (u32*)(h + (long)g * Nn_ * CCH);  // 1088 uints (pairs of bf16)
    for (int i = t; i < Nn_ * CCH / 2; i += 256) {
        u32 v = hg[i];
        hs[2 * i]     = __uint_as_float(v << 16);
        hs[2 * i + 1] = __uint_as_float(v & 0xffff0000u);
    }
    __syncthreads();
    if (t < Nn_ * 2) {
        int n = t / 2, hh = t % 2;
        float s1 = 0.f, s2 = 0.f;
        for (int d = 0; d < HID; d++) {
            float hv = hs[n * CCH + hh * HID + d];
            s1 += hv * a_src[hh * HID + d];
            s2 += hv * a_dst[hh * HID + d];
        }
        as_[t] = s1;
        ad_[t] = s2;
    }
    __syncthreads();
    if (t < Ee * 2) {
        int e = t / 2, hh = t % 2;
        float x = as_[srcA[e] * 2 + hh] + ad_[dstA[e] * 2 + hh];
        ev[t] = (x > 0.f) ? x : 0.2f * x;
    }
    __syncthreads();
    if (t < Nn_ * 2) {
        int n = t / 2, hh = t % 2;
        float m = -1e30f;
        for (int p = off[n]; p < off[n + 1]; p++) m = fmaxf(m, ev[eid[p] * 2 + hh]);
        float den = 0.f;
        for (int p = off[n]; p < off[n + 1]; p++) den += expf(ev[eid[p] * 2 + hh] - m);
        mden[t] = m;
        mden[Nn_ * 2 + t] = den;
    }
    __syncthreads();
    if (t < Ee * 2) {
        int e = t / 2, hh = t % 2;
        int n = dstA[e];
        ev[t] = expf(ev[t] - mden[n * 2 + hh]) / (mden[Nn_ * 2 + n * 2 + hh] + 1e-16f);
    }
    __syncthreads();
    for (int p = t; p < Nn_ * CCH / 2; p += 256) {
        int i0 = 2 * p;
        int n = i0 / CCH, c = i0 % CCH, hh = c >> 6;
        float a0 = 0.f, a1 = 0.f;
        for (int pp = off[n]; pp < off[n + 1]; pp++) {
            int e = eid[pp];
            float al = ev[e * 2 + hh];
            a0 += al * hs[srcA[e] * CCH + c];
            a1 += al * hs[srcA[e] * CCH + c + 1];
        }
        a0 += bias[c];
        a1 += bias[c + 1];
        if (relu_flag) { a0 = fmaxf(a0, 0.f); a1 = fmaxf(a1, 0.f); }
        hg[p] = (u32)f2bf(a0) | ((u32)f2bf(a1) << 16);
    }
}

// ---------------- LSTM recurrence: one block per batch row, whh rows in registers
template <int OBF16>
__global__ __launch_bounds__(512, 1) void k_lstm(const float* __restrict__ XW,
                                                 const float* __restrict__ whh,
                                                 void* __restrict__ hseq) {
    const int b = blockIdx.x, j = threadIdx.x;  // j in [0,512): gate column
    float4 w[32];
#pragma unroll
    for (int k = 0; k < 32; k++) w[k] = ((const float4*)(whh + (long)j * OUT_))[k];
    __shared__ __align__(16) float h_s[OUT_];
    __shared__ float c_s[OUT_];
    __shared__ float gate_s[G4];
    if (j < OUT_) { h_s[j] = 0.f; c_s[j] = 0.f; }
    __syncthreads();
    for (int t = 0; t < Tt; t++) {
        float acc = XW[((long)b * Tt + t) * G4 + j];
#pragma unroll
        for (int k = 0; k < 32; k++) {
            float4 hv = ((const float4*)h_s)[k];
            acc += w[k].x * hv.x + w[k].y * hv.y + w[k].z * hv.z + w[k].w * hv.w;
        }
        gate_s[j] = acc;
        __syncthreads();
        if (j < OUT_) {
            float gi = gate_s[j], gf = gate_s[OUT_ + j], gg = gate_s[2 * OUT_ + j], go = gate_s[3 * OUT_ + j];
            float si = 1.f / (1.f + expf(-gi));
            float sf = 1.f / (1.f + expf(-gf));
            float so = 1.f / (1.f + expf(-go));
            float c = sf * c_s[j] + si * tanhf(gg);
            float hh = so * tanhf(c);
            c_s[j] = c;
            h_s[j] = hh;
            long idx = ((long)b * Tt + t) * OUT_ + j;
            if (OBF16) ((u16*)hseq)[idx] = f2bf(hh);
            else       ((float*)hseq)[idx] = hh;
        }
        __syncthreads();
    }
}

// ---------------- attention pooling + FC: one wave per batch row
__global__ __launch_bounds__(64) void k_attn_fc(const float* __restrict__ h2,
                                                const float* __restrict__ attn_w,
                                                const float* __restrict__ attn_b,
                                                const float* __restrict__ fc_w,
                                                const float* __restrict__ fc_b,
                                                float* __restrict__ out) {
    const int b = blockIdx.x, t = threadIdx.x;
    __shared__ float aw[Tt];
    __shared__ float ctx[OUT_];
    const float* hb = h2 + (long)b * Tt * OUT_;
    float acc = 0.f;
    for (int d = 0; d < OUT_; d++) acc += hb[t * OUT_ + d] * attn_w[d];
    float sc = tanhf(acc + attn_b[0]);
    float m = sc;
#pragma unroll
    for (int o = 32; o > 0; o >>= 1) m = fmaxf(m, __shfl_xor(m, o));
    float ex = expf(sc - m);
    float sum = ex;
#pragma unroll
    for (int o = 32; o > 0; o >>= 1) sum += __shfl_xor(sum, o);
    aw[t] = ex / sum;
    __syncthreads();
    for (int d = t; d < OUT_; d += 64) {
        float c = 0.f;
        for (int tt = 0; tt < Tt; tt++) c += aw[tt] * hb[tt * OUT_ + d];
        ctx[d] = c;
    }
    __syncthreads();
    if (t < NCLS) {
        float o = fc_b[t];
        for (int d = 0; d < OUT_; d++) o += ctx[d] * fc_w[t * OUT_ + d];
        out[b * NCLS + t] = o;
    }
}

extern "C" void kernel_launch(void* const* d_in, const int* in_sizes, int n_in,
                              void* d_out, int out_size, void* d_ws, size_t ws_size,
                              hipStream_t stream) {
    const float* x          = (const float*)d_in[0];
    const int*   edge_index = (const int*)d_in[1];
    const float* gw[4]  = {(const float*)d_in[2], (const float*)d_in[6], (const float*)d_in[10], (const float*)d_in[14]};
    const float* gas[4] = {(const float*)d_in[3], (const float*)d_in[7], (const float*)d_in[11], (const float*)d_in[15]};
    const float* gad[4] = {(const float*)d_in[4], (const float*)d_in[8], (const float*)d_in[12], (const float*)d_in[16]};
    const float* gb[4]  = {(const float*)d_in[5], (const float*)d_in[9], (const float*)d_in[13], (const float*)d_in[17]};
    const float* wih0 = (const float*)d_in[18];
    const float* whh0 = (const float*)d_in[19];
    const float* bih0 = (const float*)d_in[20];
    const float* bhh0 = (const float*)d_in[21];
    const float* wih1 = (const float*)d_in[22];
    const float* whh1 = (const float*)d_in[23];
    const float* bih1 = (const float*)d_in[24];
    const float* bhh1 = (const float*)d_in[25];
    const float* attn_w = (const float*)d_in[26];
    const float* attn_b = (const float*)d_in[27];
    const float* fc_w   = (const float*)d_in[28];
    const float* fc_b   = (const float*)d_in[29];
    float* out = (float*)d_out;
    char* p = (char*)d_ws;

    // Workspace layout (~153.5 MB, all 16B-aligned; round-1 confirmed >=176 MB available)
    u16*   hbuf  = (u16*)(p + 0L);             // Mg*128 bf16           = 71,303,168 B
    float* XW0   = (float*)(p + 71303168L);    // 16384*512 f32         = 33,554,432 B
    float* XW1   = (float*)(p + 104857600L);   //                       = 33,554,432 B
    float* h2s   = (float*)(p + 138412032L);   // 16384*128 f32         =  8,388,608 B
    u16*   h1s   = (u16*)(p + 146800640L);     // 16384*128 bf16        =  4,194,304 B
    u16*   wih0b = (u16*)(p + 150994944L);     // 512*2176 bf16         =  2,228,224 B
    u16*   wih1b = (u16*)(p + 153223168L);     // 512*128 bf16          =    131,072 B
    u16*   wt1   = (u16*)(p + 153354240L);     // 128*128 bf16 (x3)
    u16*   wt2   = (u16*)(p + 153387008L);
    u16*   wt3   = (u16*)(p + 153419776L);
    int*   csr   = (int*)(p + 153452544L);     // 261 ints

    k_setup<<<1, 1, 0, stream>>>(edge_index, csr);
    k_convert_t128<<<64, 256, 0, stream>>>(gw[1], wt1);
    k_convert_t128<<<64, 256, 0, stream>>>(gw[2], wt2);
    k_convert_t128<<<64, 256, 0, stream>>>(gw[3], wt3);
    k_convert<<<(512 * 2176 + 255) / 256, 256, 0, stream>>>(wih0, wih0b, 512L * 2176);
    k_convert<<<(512 * 128 + 255) / 256, 256, 0, stream>>>(wih1, wih1b, 512L * 128);

    // GAT layer 0 (K=3, vector) + attention
    k_l0<<<Mg / 16, 256, 0, stream>>>(x, gw[0], hbuf);
    k_gat_attn<<<Gg, 256, 0, stream>>>(hbuf, gas[0], gad[0], gb[0], csr, 1);
    // GAT layers 1..3: in-place MFMA GEMM (full-width N) + attention
    k_gemm_mfma<1><<<dim3(Mg / 128, 1), 256, 0, stream>>>(hbuf, wt1, hbuf, nullptr, nullptr, 128, 128);
    k_gat_attn<<<Gg, 256, 0, stream>>>(hbuf, gas[1], gad[1], gb[1], csr, 0);
    k_gemm_mfma<1><<<dim3(Mg / 128, 1), 256, 0, stream>>>(hbuf, wt2, hbuf, nullptr, nullptr, 128, 128);
    k_gat_attn<<<Gg, 256, 0, stream>>>(hbuf, gas[2], gad[2], gb[2], csr, 1);
    k_gemm_mfma<1><<<dim3(Mg / 128, 1), 256, 0, stream>>>(hbuf, wt3, hbuf, nullptr, nullptr, 128, 128);
    k_gat_attn<<<Gg, 256, 0, stream>>>(hbuf, gas[3], gad[3], gb[3], csr, 0);

    // LSTM layer 0: hbuf viewed as [16384, 2176] bf16 -> XW0 fp32 (+biases); recurrence
    k_gemm_mfma<0><<<dim3(Gg / 128, 4), 256, 0, stream>>>(hbuf, wih0b, XW0, bih0, bhh0, LSTM_IN, G4);
    k_lstm<1><<<Bb, 512, 0, stream>>>(XW0, whh0, h1s);

    // LSTM layer 1
    k_gemm_mfma<0><<<dim3(Gg / 128, 4), 256, 0, stream>>>(h1s, wih1b, XW1, bih1, bhh1, OUT_, G4);
    k_lstm<0><<<Bb, 512, 0, stream>>>(XW1, whh1, h2s);

    // attention pooling + FC
    k_attn_fc<<<Bb, 64, 0, stream>>>(h2s, attn_w, attn_b, fc_w, fc_b, out);
}